// Round 1
// baseline (650.150 us; speedup 1.0000x reference)
//
#include <hip/hip_runtime.h>
#include <hip/hip_bf16.h>
#include <math.h>

// Problem constants
#define Bn 2
#define Lc 16384
#define Cc 192
#define NHEAD 6
#define HD 32
#define NW 64          // tokens per window
#define NWIN 512       // total windows (2 * 256)
#define HIDDEN 768
#define ROWS 32768     // B_ * N = Bn * Lc

// ---------------- LayerNorm (optionally window-partitioning writer) -------------
// One wave (64 lanes) per row; 3 elements per lane. windowed: output row r is in
// window order, source row computed via window mapping.
__global__ __launch_bounds__(256)
void ln_kernel(const float* __restrict__ src, const float* __restrict__ g,
               const float* __restrict__ b, float* __restrict__ dst, int windowed) {
    int wave = threadIdx.x >> 6;
    int lane = threadIdx.x & 63;
    int r = blockIdx.x * 4 + wave;          // output row, 0..32767
    int srow;
    if (windowed) {
        int win = r >> 6, n = r & 63;
        int bb = win >> 8, wi = win & 255;
        int s = ((wi >> 6) << 2) + (n >> 4);
        int h = (((wi >> 3) & 7) << 2) + ((n >> 2) & 3);
        int w = ((wi & 7) << 2) + (n & 3);
        srow = bb * Lc + (s << 10) + (h << 5) + w;
    } else {
        srow = r;
    }
    const float* sp = src + (size_t)srow * Cc;
    float x0 = sp[lane], x1 = sp[lane + 64], x2 = sp[lane + 128];
    float s1 = x0 + x1 + x2;
    float s2 = x0 * x0 + x1 * x1 + x2 * x2;
    #pragma unroll
    for (int off = 32; off; off >>= 1) {
        s1 += __shfl_xor(s1, off);
        s2 += __shfl_xor(s2, off);
    }
    float mean = s1 * (1.0f / 192.0f);
    float var = s2 * (1.0f / 192.0f) - mean * mean;
    float rstd = rsqrtf(var + 1e-5f);
    float* dp = dst + (size_t)r * Cc;
    dp[lane]       = (x0 - mean) * rstd * g[lane]       + b[lane];
    dp[lane + 64]  = (x1 - mean) * rstd * g[lane + 64]  + b[lane + 64];
    dp[lane + 128] = (x2 - mean) * rstd * g[lane + 128] + b[lane + 128];
}

// ---------------- Generic 64x64 fp32 GEMM with fused epilogues ----------------
// C[row][col] = sum_k A[row][k]*B[k][col] (+bias, + epilogue-specific)
enum { EPI_KV = 0, EPI_PROJ = 1, EPI_FC1 = 2, EPI_FC2 = 3 };

template <int EPI>
__global__ __launch_bounds__(256)
void gemm_kernel(const float* __restrict__ A, const float* __restrict__ Bm,
                 const float* __restrict__ bias, float* __restrict__ C,
                 int M, int N, int K,
                 const float* __restrict__ extra,   // PROJ: shortcut x; FC2: x_buf
                 float* __restrict__ C2) {          // KV: v_buf
    __shared__ float As[16][65];
    __shared__ float Bs[16][65];
    const int t = threadIdx.x;
    const int m0 = blockIdx.x * 64, n0 = blockIdx.y * 64;
    const int tx = t & 15, ty = t >> 4;
    float acc[4][4] = {};

    const int ar = t >> 2, akq = (t & 3) * 4;     // A: row ar, k quad akq
    const int bk = t >> 4, bnq = (t & 15) * 4;    // B: k row bk, n quad bnq

    for (int k0 = 0; k0 < K; k0 += 16) {
        float4 av = *(const float4*)(A + (size_t)(m0 + ar) * K + k0 + akq);
        float4 bv = *(const float4*)(Bm + (size_t)(k0 + bk) * N + n0 + bnq);
        As[akq + 0][ar] = av.x; As[akq + 1][ar] = av.y;
        As[akq + 2][ar] = av.z; As[akq + 3][ar] = av.w;
        Bs[bk][bnq + 0] = bv.x; Bs[bk][bnq + 1] = bv.y;
        Bs[bk][bnq + 2] = bv.z; Bs[bk][bnq + 3] = bv.w;
        __syncthreads();
        #pragma unroll
        for (int k = 0; k < 16; k++) {
            float a[4], bb[4];
            #pragma unroll
            for (int i = 0; i < 4; i++) a[i] = As[k][ty * 4 + i];
            #pragma unroll
            for (int j = 0; j < 4; j++) bb[j] = Bs[k][tx * 4 + j];
            #pragma unroll
            for (int i = 0; i < 4; i++)
                #pragma unroll
                for (int j = 0; j < 4; j++) acc[i][j] += a[i] * bb[j];
        }
        __syncthreads();
    }

    #pragma unroll
    for (int i = 0; i < 4; i++) {
        int row = m0 + ty * 4 + i;
        #pragma unroll
        for (int j = 0; j < 4; j++) {
            int col = n0 + tx * 4 + j;
            float v = acc[i][j] + bias[col];
            if constexpr (EPI == EPI_KV) {
                // col in [0,384): kvsel, head, d ; scatter to [win][head][n][d]
                int kvsel = col >= 192;
                int c = col - (kvsel ? 192 : 0);
                int head = c >> 5, d = c & 31;
                float* dst = kvsel ? C2 : C;
                dst[((size_t)((row >> 6) * NHEAD + head) << 11) + ((row & 63) << 5) + d] = v;
            } else if constexpr (EPI == EPI_PROJ) {
                // window-reverse + residual with shortcut x
                int win = row >> 6, n = row & 63;
                int bb2 = win >> 8, wi = win & 255;
                int s = ((wi >> 6) << 2) + (n >> 4);
                int h = (((wi >> 3) & 7) << 2) + ((n >> 2) & 3);
                int w = ((wi & 7) << 2) + (n & 3);
                size_t gidx = ((size_t)bb2 * Lc + (s << 10) + (h << 5) + w) * Cc + col;
                C[gidx] = extra[gidx] + v;
            } else if constexpr (EPI == EPI_FC1) {
                // exact-erf GELU
                float gl = 0.5f * v * (1.0f + erff(v * 0.70710678118654752f));
                C[(size_t)row * N + col] = gl;
            } else { // EPI_FC2
                size_t gidx = (size_t)row * N + col;
                C[gidx] = v + extra[gidx];
            }
        }
    }
}

// ---------------- Windowed attention: one wave per (window, head) -------------
__global__ __launch_bounds__(64)
void attn_kernel(const float* __restrict__ q_src, const float* __restrict__ kbuf,
                 const float* __restrict__ vbuf, const float* __restrict__ rpb,
                 float* __restrict__ out) {
    const int win = blockIdx.x, head = blockIdx.y;
    const int lane = threadIdx.x;           // token n within window
    __shared__ float kl[NW][HD];
    __shared__ float vl[NW][HD];
    __shared__ float bl[343];
    const float* kp = kbuf + ((size_t)(win * NHEAD + head) << 11);
    const float* vp = vbuf + ((size_t)(win * NHEAD + head) << 11);
    for (int i = lane; i < NW * HD; i += 64) {
        ((float*)kl)[i] = kp[i];
        ((float*)vl)[i] = vp[i];
    }
    for (int i = lane; i < 343; i += 64) bl[i] = rpb[i * NHEAD + head];
    __syncthreads();

    const float scale = 0.17677669529663687f;   // 1/sqrt(32)
    float q[HD];
    const float* qp = q_src + ((size_t)(win * NW + lane)) * Cc + head * HD;
    #pragma unroll
    for (int d = 0; d < HD; d++) q[d] = qp[d] * scale;

    const int is_n = lane >> 4, ih_n = (lane >> 2) & 3, iw_n = lane & 3;

    // pass 1: row max of (q.k + bias)
    float mx = -1e30f;
    for (int m = 0; m < NW; m++) {
        float dot = 0.0f;
        #pragma unroll
        for (int d = 0; d < HD; d++) dot += q[d] * kl[m][d];
        int idx = (is_n - (m >> 4) + 3) * 11 + (ih_n - ((m >> 2) & 3) + 3) * 7 + (iw_n - (m & 3) + 3);
        dot += bl[idx];
        mx = fmaxf(mx, dot);
    }
    // pass 2: exp + accumulate P@V
    float accv[HD];
    #pragma unroll
    for (int d = 0; d < HD; d++) accv[d] = 0.0f;
    float sum = 0.0f;
    for (int m = 0; m < NW; m++) {
        float dot = 0.0f;
        #pragma unroll
        for (int d = 0; d < HD; d++) dot += q[d] * kl[m][d];
        int idx = (is_n - (m >> 4) + 3) * 11 + (ih_n - ((m >> 2) & 3) + 3) * 7 + (iw_n - (m & 3) + 3);
        float p = __expf(dot + bl[idx] - mx);
        sum += p;
        #pragma unroll
        for (int d = 0; d < HD; d++) accv[d] += p * vl[m][d];
    }
    float inv = 1.0f / sum;
    float* op = out + ((size_t)(win * NW + lane)) * Cc + head * HD;
    #pragma unroll
    for (int d = 0; d < HD; d++) op[d] = accv[d] * inv;
}

// -------------------------------- launcher ------------------------------------
extern "C" void kernel_launch(void* const* d_in, const int* in_sizes, int n_in,
                              void* d_out, int out_size, void* d_ws, size_t ws_size,
                              hipStream_t stream) {
    const float* x      = (const float*)d_in[0];
    // d_in[1] = mask_matrix (unused: shift_size == 0)
    const float* skip   = (const float*)d_in[2];
    const float* x_up   = (const float*)d_in[3];
    const float* n1g    = (const float*)d_in[4];
    const float* n1b    = (const float*)d_in[5];
    const float* kv_w   = (const float*)d_in[6];
    const float* kv_b   = (const float*)d_in[7];
    const float* rpb    = (const float*)d_in[8];
    const float* proj_w = (const float*)d_in[9];
    const float* proj_b = (const float*)d_in[10];
    const float* n2g    = (const float*)d_in[11];
    const float* n2b    = (const float*)d_in[12];
    const float* fc1_w  = (const float*)d_in[13];
    const float* fc1_b  = (const float*)d_in[14];
    const float* fc2_w  = (const float*)d_in[15];
    const float* fc2_b  = (const float*)d_in[16];
    float* out = (float*)d_out;

    const size_t CH = (size_t)ROWS * Cc;    // 6,291,456 floats = 25.17 MB
    float* W0 = (float*)d_ws;               // skip_w ; later h1[0]
    float* W1 = W0 + CH;                    // xup_w  ; later h1[1]
    float* W2 = W1 + CH;                    // k_buf  ; later h1[2]
    float* W3 = W2 + CH;                    // v_buf  ; later h1[3]
    float* W4 = W3 + CH;                    // attn_out ; later h_norm
    float* W5 = W4 + CH;                    // x_buf (lives to end)

    float* skip_w  = W0;
    float* xup_w   = W1;
    float* k_buf   = W2;
    float* v_buf   = W3;
    float* attn_o  = W4;
    float* x_buf   = W5;
    float* h_norm  = W4;   // reuses attn_out after proj
    float* h1      = W0;   // contiguous 4 chunks W0..W3 (32768 x 768)

    // 1-2: LN + window partition of skip and x_up
    ln_kernel<<<ROWS / 4, 256, 0, stream>>>(skip, n1g, n1b, skip_w, 1);
    ln_kernel<<<ROWS / 4, 256, 0, stream>>>(x_up, n1g, n1b, xup_w, 1);
    // 3: kv = skip_w @ kv_w + kv_b, scattered to k/v [win][head][n][d]
    gemm_kernel<EPI_KV><<<dim3(ROWS / 64, 384 / 64), 256, 0, stream>>>(
        skip_w, kv_w, kv_b, k_buf, ROWS, 384, Cc, nullptr, v_buf);
    // 4: windowed attention
    attn_kernel<<<dim3(NWIN, NHEAD), 64, 0, stream>>>(xup_w, k_buf, v_buf, rpb, attn_o);
    // 5: proj + window reverse + residual (shortcut = x)
    gemm_kernel<EPI_PROJ><<<dim3(ROWS / 64, Cc / 64), 256, 0, stream>>>(
        attn_o, proj_w, proj_b, x_buf, ROWS, Cc, Cc, x, nullptr);
    // 6: LN for MLP
    ln_kernel<<<ROWS / 4, 256, 0, stream>>>(x_buf, n2g, n2b, h_norm, 0);
    // 7: fc1 + GELU
    gemm_kernel<EPI_FC1><<<dim3(ROWS / 64, HIDDEN / 64), 256, 0, stream>>>(
        h_norm, fc1_w, fc1_b, h1, ROWS, HIDDEN, Cc, nullptr, nullptr);
    // 8: fc2 + residual -> out
    gemm_kernel<EPI_FC2><<<dim3(ROWS / 64, Cc / 64), 256, 0, stream>>>(
        h1, fc2_w, fc2_b, out, ROWS, Cc, HIDDEN, x_buf, nullptr);
}

// Round 2
// 218.994 us; speedup vs baseline: 2.9688x; 2.9688x over previous
//
#include <hip/hip_runtime.h>
#include <hip/hip_bf16.h>
#include <math.h>

#define Bn 2
#define Lc 16384
#define Cc 192
#define NHEAD 6
#define HD 32
#define NW 64
#define NWIN 512
#define HIDDEN 768
#define ROWS 32768

typedef __attribute__((ext_vector_type(8))) short short8;
typedef __attribute__((ext_vector_type(4))) float f32x4;

__device__ __forceinline__ ushort f2bf(float f) {
    uint u = __float_as_uint(f);
    return (ushort)((u + 0x7fffu + ((u >> 16) & 1u)) >> 16);
}
__device__ __forceinline__ float bf2f(ushort u) {
    return __uint_as_float(((uint)u) << 16);
}
__device__ __forceinline__ void gload16(const void* g, void* l) {
    __builtin_amdgcn_global_load_lds(
        (const __attribute__((address_space(1))) void*)g,
        (__attribute__((address_space(3))) void*)l, 16, 0, 0);
}

// ---------------- weight pack: fp32 [K][N] -> bf16 Bp[k/8][n][8] ----------------
__global__ __launch_bounds__(256)
void pack_w(const float* __restrict__ W, ushort* __restrict__ out, int KN, int N) {
    int idx = blockIdx.x * 256 + threadIdx.x;
    if (idx < KN) {
        int k = idx / N, n = idx - k * N;
        out[((size_t)(k >> 3) * N + n) * 8 + (k & 7)] = f2bf(W[idx]);
    }
}

// ---------------- LayerNorm -> bf16 (optional window partition) -----------------
__global__ __launch_bounds__(256)
void ln_kernel(const float* __restrict__ src, const float* __restrict__ g,
               const float* __restrict__ b, ushort* __restrict__ dst, int windowed) {
    int wave = threadIdx.x >> 6;
    int lane = threadIdx.x & 63;
    int r = blockIdx.x * 4 + wave;
    int srow;
    if (windowed) {
        int win = r >> 6, n = r & 63;
        int bb = win >> 8, wi = win & 255;
        int s = ((wi >> 6) << 2) + (n >> 4);
        int h = (((wi >> 3) & 7) << 2) + ((n >> 2) & 3);
        int w = ((wi & 7) << 2) + (n & 3);
        srow = bb * Lc + (s << 10) + (h << 5) + w;
    } else {
        srow = r;
    }
    const float* sp = src + (size_t)srow * Cc;
    float x0 = sp[lane], x1 = sp[lane + 64], x2 = sp[lane + 128];
    float s1 = x0 + x1 + x2;
    float s2 = x0 * x0 + x1 * x1 + x2 * x2;
    #pragma unroll
    for (int off = 32; off; off >>= 1) {
        s1 += __shfl_xor(s1, off);
        s2 += __shfl_xor(s2, off);
    }
    float mean = s1 * (1.0f / 192.0f);
    float var = s2 * (1.0f / 192.0f) - mean * mean;
    float rstd = rsqrtf(var + 1e-5f);
    ushort* dp = dst + (size_t)r * Cc;
    dp[lane]       = f2bf((x0 - mean) * rstd * g[lane]       + b[lane]);
    dp[lane + 64]  = f2bf((x1 - mean) * rstd * g[lane + 64]  + b[lane + 64]);
    dp[lane + 128] = f2bf((x2 - mean) * rstd * g[lane + 128] + b[lane + 128]);
}

// ---------------- bf16 MFMA GEMM, 128x64 tile, fused epilogues ------------------
// A: bf16 [M][K]; Bp: bf16 packed [K/8][N][8]; accum fp32.
enum { EPI_KV = 0, EPI_PROJ = 1, EPI_FC1 = 2, EPI_FC2 = 3 };

template <int EPI>
__global__ __launch_bounds__(256)
void mgemm(const ushort* __restrict__ A, const ushort* __restrict__ Bp,
           const float* __restrict__ bias, float* __restrict__ C,
           int M, int N, int K, const float* __restrict__ extra,
           float* __restrict__ C2, ushort* __restrict__ Cb) {
    __shared__ ushort Als[4][128][8];   // [k-slot][row][8k]  8 KB
    __shared__ ushort Bls[4][64][8];    // [k-slot][col][8k]  4 KB
    const int t = threadIdx.x, lane = t & 63, w = t >> 6;
    const int wm = w >> 1, wn = w & 1;
    const int m0 = blockIdx.x * 128, n0 = blockIdx.y * 64;
    f32x4 acc[4][2] = {};

    // staging: wave w stages A slot w (rows 0-63, 64-127) + B slot w
    const ushort* gA0 = A + (size_t)(m0 + lane) * K + w * 8;
    const ushort* gA1 = A + (size_t)(m0 + 64 + lane) * K + w * 8;
    const ushort* gB0 = Bp + ((size_t)w * N + n0 + lane) * 8;
    const int fr = lane & 15, fs = lane >> 4;

    for (int k0 = 0; k0 < K; k0 += 32) {
        gload16(gA0 + k0, &Als[w][0][0]);
        gload16(gA1 + k0, &Als[w][64][0]);
        gload16(gB0 + (size_t)k0 * N, &Bls[w][0][0]);
        __syncthreads();
        short8 a[4], b[2];
        #pragma unroll
        for (int mf = 0; mf < 4; mf++)
            a[mf] = *(const short8*)&Als[fs][wm * 64 + mf * 16 + fr][0];
        #pragma unroll
        for (int nf = 0; nf < 2; nf++)
            b[nf] = *(const short8*)&Bls[fs][wn * 32 + nf * 16 + fr][0];
        #pragma unroll
        for (int mf = 0; mf < 4; mf++)
            #pragma unroll
            for (int nf = 0; nf < 2; nf++)
                acc[mf][nf] = __builtin_amdgcn_mfma_f32_16x16x32_bf16(
                    a[mf], b[nf], acc[mf][nf], 0, 0, 0);
        __syncthreads();
    }

    #pragma unroll
    for (int mf = 0; mf < 4; mf++) {
        #pragma unroll
        for (int nf = 0; nf < 2; nf++) {
            #pragma unroll
            for (int r = 0; r < 4; r++) {
                int row = m0 + wm * 64 + mf * 16 + fs * 4 + r;
                int col = n0 + wn * 32 + nf * 16 + fr;
                float v = acc[mf][nf][r] + bias[col];
                if constexpr (EPI == EPI_KV) {
                    int kvsel = col >= 192;
                    int c = col - (kvsel ? 192 : 0);
                    int head = c >> 5, d = c & 31;
                    float* dst = kvsel ? C2 : C;
                    dst[((size_t)((row >> 6) * NHEAD + head) << 11) + ((row & 63) << 5) + d] = v;
                } else if constexpr (EPI == EPI_PROJ) {
                    int win = row >> 6, n = row & 63;
                    int bb2 = win >> 8, wi = win & 255;
                    int s = ((wi >> 6) << 2) + (n >> 4);
                    int h = (((wi >> 3) & 7) << 2) + ((n >> 2) & 3);
                    int ww = ((wi & 7) << 2) + (n & 3);
                    size_t gidx = ((size_t)bb2 * Lc + (s << 10) + (h << 5) + ww) * Cc + col;
                    C[gidx] = extra[gidx] + v;
                } else if constexpr (EPI == EPI_FC1) {
                    float gl = 0.5f * v * (1.0f + erff(v * 0.70710678118654752f));
                    Cb[(size_t)row * N + col] = f2bf(gl);
                } else {
                    size_t gidx = (size_t)row * N + col;
                    C[gidx] = v + extra[gidx];
                }
            }
        }
    }
}

// ---------------- windowed attention: one wave per (window, head) ---------------
__global__ __launch_bounds__(64)
void attn_kernel(const ushort* __restrict__ q_src, const float* __restrict__ kbuf,
                 const float* __restrict__ vbuf, const float* __restrict__ rpb,
                 ushort* __restrict__ out) {
    const int win = blockIdx.x, head = blockIdx.y;
    const int lane = threadIdx.x;
    __shared__ __align__(16) float kl[NW][HD];
    __shared__ __align__(16) float vl[NW][HD];
    __shared__ float bl[343];
    const float* kp = kbuf + ((size_t)(win * NHEAD + head) << 11);
    const float* vp = vbuf + ((size_t)(win * NHEAD + head) << 11);
    for (int i = lane; i < NW * HD / 4; i += 64) {
        ((float4*)kl)[i] = ((const float4*)kp)[i];
        ((float4*)vl)[i] = ((const float4*)vp)[i];
    }
    for (int i = lane; i < 343; i += 64) bl[i] = rpb[i * NHEAD + head];
    __syncthreads();

    const float scale = 0.17677669529663687f;
    float q[HD];
    const short8* qp8 = (const short8*)(q_src + ((size_t)(win * NW + lane)) * Cc + head * HD);
    #pragma unroll
    for (int i = 0; i < 4; i++) {
        short8 v8 = qp8[i];
        #pragma unroll
        for (int j = 0; j < 8; j++) q[i * 8 + j] = bf2f((ushort)v8[j]) * scale;
    }

    const int is_n = lane >> 4, ih_n = (lane >> 2) & 3, iw_n = lane & 3;

    float mx = -1e30f;
    for (int m = 0; m < NW; m++) {
        float dot = 0.0f;
        #pragma unroll
        for (int d = 0; d < HD; d++) dot += q[d] * kl[m][d];
        int idx = (is_n - (m >> 4) + 3) * 11 + (ih_n - ((m >> 2) & 3) + 3) * 7 + (iw_n - (m & 3) + 3);
        dot += bl[idx];
        mx = fmaxf(mx, dot);
    }
    float accv[HD];
    #pragma unroll
    for (int d = 0; d < HD; d++) accv[d] = 0.0f;
    float sum = 0.0f;
    for (int m = 0; m < NW; m++) {
        float dot = 0.0f;
        #pragma unroll
        for (int d = 0; d < HD; d++) dot += q[d] * kl[m][d];
        int idx = (is_n - (m >> 4) + 3) * 11 + (ih_n - ((m >> 2) & 3) + 3) * 7 + (iw_n - (m & 3) + 3);
        float p = __expf(dot + bl[idx] - mx);
        sum += p;
        #pragma unroll
        for (int d = 0; d < HD; d++) accv[d] += p * vl[m][d];
    }
    float inv = 1.0f / sum;
    ushort* op = out + ((size_t)(win * NW + lane)) * Cc + head * HD;
    #pragma unroll
    for (int i = 0; i < 4; i++) {
        short8 o8;
        #pragma unroll
        for (int j = 0; j < 8; j++) o8[j] = (short)f2bf(accv[i * 8 + j] * inv);
        ((short8*)op)[i] = o8;
    }
}

// -------------------------------- launcher --------------------------------------
extern "C" void kernel_launch(void* const* d_in, const int* in_sizes, int n_in,
                              void* d_out, int out_size, void* d_ws, size_t ws_size,
                              hipStream_t stream) {
    const float* x      = (const float*)d_in[0];
    const float* skip   = (const float*)d_in[2];
    const float* x_up   = (const float*)d_in[3];
    const float* n1g    = (const float*)d_in[4];
    const float* n1b    = (const float*)d_in[5];
    const float* kv_w   = (const float*)d_in[6];
    const float* kv_b   = (const float*)d_in[7];
    const float* rpb    = (const float*)d_in[8];
    const float* proj_w = (const float*)d_in[9];
    const float* proj_b = (const float*)d_in[10];
    const float* n2g    = (const float*)d_in[11];
    const float* n2b    = (const float*)d_in[12];
    const float* fc1_w  = (const float*)d_in[13];
    const float* fc1_b  = (const float*)d_in[14];
    const float* fc2_w  = (const float*)d_in[15];
    const float* fc2_b  = (const float*)d_in[16];
    float* out = (float*)d_out;

    char* ws = (char*)d_ws;
    ushort* skip_w = (ushort*)ws;                       // 12,582,912 B
    ushort* xup_w  = (ushort*)(ws + 12582912);          // 12,582,912
    float*  k_buf  = (float*)(ws + 25165824);           // 25,165,824
    float*  v_buf  = (float*)(ws + 50331648);           // 25,165,824
    ushort* attn_o = (ushort*)(ws + 75497472);          // 12,582,912
    float*  x_buf  = (float*)(ws + 88080384);           // 25,165,824
    ushort* h_norm = (ushort*)(ws + 113246208);         // 12,582,912
    ushort* h1     = (ushort*)ws;                       // 50,331,648 (overlays skip_w..k_buf, dead by then)
    char* wp = ws + 125829120;
    ushort* kv_wp   = (ushort*)wp;                      // 147,456
    ushort* proj_wp = (ushort*)(wp + 147456);           // 73,728
    ushort* fc1_wp  = (ushort*)(wp + 221184);           // 294,912
    ushort* fc2_wp  = (ushort*)(wp + 516096);           // 294,912

    // weight packing (tiny)
    pack_w<<<(192 * 384 + 255) / 256, 256, 0, stream>>>(kv_w, kv_wp, 192 * 384, 384);
    pack_w<<<(192 * 192 + 255) / 256, 256, 0, stream>>>(proj_w, proj_wp, 192 * 192, 192);
    pack_w<<<(192 * 768 + 255) / 256, 256, 0, stream>>>(fc1_w, fc1_wp, 192 * 768, 768);
    pack_w<<<(768 * 192 + 255) / 256, 256, 0, stream>>>(fc2_w, fc2_wp, 768 * 192, 192);

    // LN + window partition -> bf16
    ln_kernel<<<ROWS / 4, 256, 0, stream>>>(skip, n1g, n1b, skip_w, 1);
    ln_kernel<<<ROWS / 4, 256, 0, stream>>>(x_up, n1g, n1b, xup_w, 1);
    // kv GEMM (scatter k/v fp32)
    mgemm<EPI_KV><<<dim3(ROWS / 128, 384 / 64), 256, 0, stream>>>(
        skip_w, kv_wp, kv_b, k_buf, ROWS, 384, Cc, nullptr, v_buf, nullptr);
    // attention
    attn_kernel<<<dim3(NWIN, NHEAD), 64, 0, stream>>>(xup_w, k_buf, v_buf, rpb, attn_o);
    // proj + window-reverse + residual
    mgemm<EPI_PROJ><<<dim3(ROWS / 128, Cc / 64), 256, 0, stream>>>(
        attn_o, proj_wp, proj_b, x_buf, ROWS, Cc, Cc, x, nullptr, nullptr);
    // LN2 -> bf16
    ln_kernel<<<ROWS / 4, 256, 0, stream>>>(x_buf, n2g, n2b, h_norm, 0);
    // fc1 + GELU -> bf16
    mgemm<EPI_FC1><<<dim3(ROWS / 128, HIDDEN / 64), 256, 0, stream>>>(
        h_norm, fc1_wp, fc1_b, nullptr, ROWS, HIDDEN, Cc, nullptr, nullptr, h1);
    // fc2 + residual -> out
    mgemm<EPI_FC2><<<dim3(ROWS / 128, Cc / 64), 256, 0, stream>>>(
        h1, fc2_wp, fc2_b, out, ROWS, Cc, HIDDEN, x_buf, nullptr, nullptr);
}

// Round 3
// 160.608 us; speedup vs baseline: 4.0480x; 1.3635x over previous
//
#include <hip/hip_runtime.h>
#include <hip/hip_bf16.h>
#include <math.h>

#define Bn 2
#define Lc 16384
#define Cc 192
#define NHEAD 6
#define HD 32
#define NW 64
#define NWIN 512
#define HIDDEN 768
#define ROWS 32768

typedef __attribute__((ext_vector_type(8))) short short8;
typedef __attribute__((ext_vector_type(4))) float f32x4;

__device__ __forceinline__ ushort f2bf(float f) {
    uint u = __float_as_uint(f);
    return (ushort)((u + 0x7fffu + ((u >> 16) & 1u)) >> 16);
}
__device__ __forceinline__ void gload16(const void* g, void* l) {
    __builtin_amdgcn_global_load_lds(
        (const __attribute__((address_space(1))) void*)g,
        (__attribute__((address_space(3))) void*)l, 16, 0, 0);
}

// ---------------- weight pack: fp32 [K][N] -> bf16 Bp[k/8][n][8] ----------------
__global__ __launch_bounds__(256)
void pack_w(const float* __restrict__ W, ushort* __restrict__ out, int KN, int N) {
    int idx = blockIdx.x * 256 + threadIdx.x;
    if (idx < KN) {
        int k = idx / N, n = idx - k * N;
        out[((size_t)(k >> 3) * N + n) * 8 + (k & 7)] = f2bf(W[idx]);
    }
}

// ------- bias pack: rpb[343][6] -> biasF[head][nf][mf][lane][r] fp32 ------------
__global__ __launch_bounds__(256)
void pack_bias(const float* __restrict__ rpb, float* __restrict__ biasF) {
    int t = blockIdx.x * 256 + threadIdx.x;      // over 6*4*4*64 = 6144
    if (t >= 6144) return;
    int lane = t & 63, mf = (t >> 6) & 3, nf = (t >> 8) & 3, head = t >> 10;
    int m = mf * 16 + (lane & 15);
    int g = lane >> 4;
    int qs = m >> 4, qh = (m >> 2) & 3, qw = m & 3;
    #pragma unroll
    for (int r = 0; r < 4; r++) {
        int n = nf * 16 + 4 * g + r;
        int ks = n >> 4, kh = (n >> 2) & 3, kw = n & 3;
        int idx = (qs - ks + 3) * 11 + (qh - kh + 3) * 7 + (qw - kw + 3);
        biasF[(size_t)t * 4 + r] = rpb[idx * NHEAD + head];
    }
}

// ---------------- LayerNorm -> bf16 (optional window partition) -----------------
__global__ __launch_bounds__(256)
void ln_kernel(const float* __restrict__ src, const float* __restrict__ g,
               const float* __restrict__ b, ushort* __restrict__ dst, int windowed) {
    int wave = threadIdx.x >> 6;
    int lane = threadIdx.x & 63;
    int r = blockIdx.x * 4 + wave;
    int srow;
    if (windowed) {
        int win = r >> 6, n = r & 63;
        int bb = win >> 8, wi = win & 255;
        int s = ((wi >> 6) << 2) + (n >> 4);
        int h = (((wi >> 3) & 7) << 2) + ((n >> 2) & 3);
        int w = ((wi & 7) << 2) + (n & 3);
        srow = bb * Lc + (s << 10) + (h << 5) + w;
    } else {
        srow = r;
    }
    const float* sp = src + (size_t)srow * Cc;
    float x0 = sp[lane], x1 = sp[lane + 64], x2 = sp[lane + 128];
    float s1 = x0 + x1 + x2;
    float s2 = x0 * x0 + x1 * x1 + x2 * x2;
    #pragma unroll
    for (int off = 32; off; off >>= 1) {
        s1 += __shfl_xor(s1, off);
        s2 += __shfl_xor(s2, off);
    }
    float mean = s1 * (1.0f / 192.0f);
    float var = s2 * (1.0f / 192.0f) - mean * mean;
    float rstd = rsqrtf(var + 1e-5f);
    ushort* dp = dst + (size_t)r * Cc;
    dp[lane]       = f2bf((x0 - mean) * rstd * g[lane]       + b[lane]);
    dp[lane + 64]  = f2bf((x1 - mean) * rstd * g[lane + 64]  + b[lane + 64]);
    dp[lane + 128] = f2bf((x2 - mean) * rstd * g[lane + 128] + b[lane + 128]);
}

// ---------------- bf16 MFMA GEMM, 128x64 tile, fused epilogues ------------------
enum { EPI_KV = 0, EPI_PROJ = 1, EPI_FC1 = 2, EPI_FC2 = 3 };

template <int EPI>
__global__ __launch_bounds__(256)
void mgemm(const ushort* __restrict__ A, const ushort* __restrict__ Bp,
           const float* __restrict__ bias, float* __restrict__ C,
           int M, int N, int K, const float* __restrict__ extra,
           ushort* __restrict__ Cb, ushort* __restrict__ Cb2) {
    __shared__ ushort Als[4][128][8];
    __shared__ ushort Bls[4][64][8];
    const int t = threadIdx.x, lane = t & 63, w = t >> 6;
    const int wm = w >> 1, wn = w & 1;
    const int m0 = blockIdx.x * 128, n0 = blockIdx.y * 64;
    f32x4 acc[4][2] = {};

    const ushort* gA0 = A + (size_t)(m0 + lane) * K + w * 8;
    const ushort* gA1 = A + (size_t)(m0 + 64 + lane) * K + w * 8;
    const ushort* gB0 = Bp + ((size_t)w * N + n0 + lane) * 8;
    const int fr = lane & 15, fs = lane >> 4;

    for (int k0 = 0; k0 < K; k0 += 32) {
        gload16(gA0 + k0, &Als[w][0][0]);
        gload16(gA1 + k0, &Als[w][64][0]);
        gload16(gB0 + (size_t)k0 * N, &Bls[w][0][0]);
        __syncthreads();
        short8 a[4], b[2];
        #pragma unroll
        for (int mf = 0; mf < 4; mf++)
            a[mf] = *(const short8*)&Als[fs][wm * 64 + mf * 16 + fr][0];
        #pragma unroll
        for (int nf = 0; nf < 2; nf++)
            b[nf] = *(const short8*)&Bls[fs][wn * 32 + nf * 16 + fr][0];
        #pragma unroll
        for (int mf = 0; mf < 4; mf++)
            #pragma unroll
            for (int nf = 0; nf < 2; nf++)
                acc[mf][nf] = __builtin_amdgcn_mfma_f32_16x16x32_bf16(
                    a[mf], b[nf], acc[mf][nf], 0, 0, 0);
        __syncthreads();
    }

    #pragma unroll
    for (int mf = 0; mf < 4; mf++) {
        #pragma unroll
        for (int nf = 0; nf < 2; nf++) {
            #pragma unroll
            for (int r = 0; r < 4; r++) {
                int row = m0 + wm * 64 + mf * 16 + fs * 4 + r;
                int col = n0 + wn * 32 + nf * 16 + fr;
                float v = acc[mf][nf][r] + bias[col];
                if constexpr (EPI == EPI_KV) {
                    int kvsel = col >= 192;
                    int c = col - (kvsel ? 192 : 0);
                    int head = c >> 5, d = c & 31;
                    int win = row >> 6, n = row & 63;
                    if (!kvsel)  // k: [win][head][n][d], pre-scaled
                        Cb[((size_t)((win * NHEAD + head) * 64 + n) << 5) + d] =
                            f2bf(v * 0.17677669529663687f);
                    else         // v transposed: [win][head][d][n]
                        Cb2[((size_t)((win * NHEAD + head) * 32 + d) << 6) + n] = f2bf(v);
                } else if constexpr (EPI == EPI_PROJ) {
                    int win = row >> 6, n = row & 63;
                    int bb2 = win >> 8, wi = win & 255;
                    int s = ((wi >> 6) << 2) + (n >> 4);
                    int h = (((wi >> 3) & 7) << 2) + ((n >> 2) & 3);
                    int ww = ((wi & 7) << 2) + (n & 3);
                    size_t gidx = ((size_t)bb2 * Lc + (s << 10) + (h << 5) + ww) * Cc + col;
                    C[gidx] = extra[gidx] + v;
                } else if constexpr (EPI == EPI_FC1) {
                    float gl = 0.5f * v * (1.0f + erff(v * 0.70710678118654752f));
                    Cb[(size_t)row * N + col] = f2bf(gl);
                } else {
                    size_t gidx = (size_t)row * N + col;
                    C[gidx] = v + extra[gidx];
                }
            }
        }
    }
}

// ----------- MFMA windowed attention: one wave per (window, head) ---------------
__global__ __launch_bounds__(256)
void attn_kernel(const ushort* __restrict__ q_src, const ushort* __restrict__ kbuf,
                 const ushort* __restrict__ vbuf, const float* __restrict__ biasF,
                 ushort* __restrict__ out) {
    __shared__ ushort P_lds[4][64][72];   // +8 pad: 16B-aligned rows, no bank conflict
    const int w = threadIdx.x >> 6, lane = threadIdx.x & 63;
    const int W = blockIdx.x * 4 + w;           // 0..3071
    const int win = W / 6, head = W % 6;
    const int lo = lane & 15, g = lane >> 4;

    const ushort* kp = kbuf + ((size_t)W << 11);   // [64 n][32 d] bf16, pre-scaled
    const ushort* vp = vbuf + ((size_t)W << 11);   // [32 d][64 n] bf16 (transposed)
    const ushort* qp = q_src + (size_t)(win * 64) * Cc + head * HD;

    // ---- QK^T: S^T[n][m] = sum_d K[n][d] * Q[m][d] ----
    short8 kf[4], qf[4];
    #pragma unroll
    for (int i = 0; i < 4; i++) {
        kf[i] = *(const short8*)(kp + ((i * 16 + lo) << 5) + (g << 3));
        qf[i] = *(const short8*)(qp + (size_t)(i * 16 + lo) * Cc + (g << 3));
    }
    f32x4 s[4][4];   // [nf][mf]
    const f32x4 zero = {0.f, 0.f, 0.f, 0.f};
    #pragma unroll
    for (int nf = 0; nf < 4; nf++)
        #pragma unroll
        for (int mf = 0; mf < 4; mf++)
            s[nf][mf] = __builtin_amdgcn_mfma_f32_16x16x32_bf16(kf[nf], qf[mf], zero, 0, 0, 0);

    // ---- bias add (pre-expanded in fragment layout) ----
    const float* bF = biasF + (size_t)head * 4096;   // 4*4*64*4
    #pragma unroll
    for (int nf = 0; nf < 4; nf++)
        #pragma unroll
        for (int mf = 0; mf < 4; mf++) {
            f32x4 b4 = *(const f32x4*)(bF + ((nf * 4 + mf) * 64 + lane) * 4);
            s[nf][mf] += b4;
        }

    // ---- softmax over n (rows of S^T), normalize, pack P -> LDS ----
    #pragma unroll
    for (int mf = 0; mf < 4; mf++) {
        float mx = -1e30f;
        #pragma unroll
        for (int nf = 0; nf < 4; nf++)
            #pragma unroll
            for (int r = 0; r < 4; r++) mx = fmaxf(mx, s[nf][mf][r]);
        mx = fmaxf(mx, __shfl_xor(mx, 16));
        mx = fmaxf(mx, __shfl_xor(mx, 32));
        float sum = 0.f;
        #pragma unroll
        for (int nf = 0; nf < 4; nf++)
            #pragma unroll
            for (int r = 0; r < 4; r++) {
                float e = __expf(s[nf][mf][r] - mx);
                s[nf][mf][r] = e;
                sum += e;
            }
        sum += __shfl_xor(sum, 16);
        sum += __shfl_xor(sum, 32);
        float inv = 1.0f / sum;
        #pragma unroll
        for (int nf = 0; nf < 4; nf++) {
            uint lo32 = (uint)f2bf(s[nf][mf][0] * inv) | ((uint)f2bf(s[nf][mf][1] * inv) << 16);
            uint hi32 = (uint)f2bf(s[nf][mf][2] * inv) | ((uint)f2bf(s[nf][mf][3] * inv) << 16);
            *(uint2*)&P_lds[w][16 * mf + lo][16 * nf + 4 * g] = make_uint2(lo32, hi32);
        }
    }
    __syncthreads();

    // ---- PV: O[m][d] = sum_n P[m][n] V[n][d] ----
    short8 vf[2][2];
    #pragma unroll
    for (int ks = 0; ks < 2; ks++)
        #pragma unroll
        for (int df = 0; df < 2; df++)
            vf[ks][df] = *(const short8*)(vp + ((df * 16 + lo) << 6) + ks * 32 + (g << 3));
    f32x4 o[4][2] = {};
    #pragma unroll
    for (int mf = 0; mf < 4; mf++)
        #pragma unroll
        for (int ks = 0; ks < 2; ks++) {
            short8 pa = *(const short8*)&P_lds[w][16 * mf + lo][ks * 32 + 8 * g];
            #pragma unroll
            for (int df = 0; df < 2; df++)
                o[mf][df] = __builtin_amdgcn_mfma_f32_16x16x32_bf16(pa, vf[ks][df], o[mf][df], 0, 0, 0);
        }

    // ---- write O (bf16, row-major [B_*N][C]) ----
    ushort* op = out + (size_t)(win * 64) * Cc + head * HD;
    #pragma unroll
    for (int mf = 0; mf < 4; mf++)
        #pragma unroll
        for (int df = 0; df < 2; df++)
            #pragma unroll
            for (int r = 0; r < 4; r++)
                op[(size_t)(16 * mf + 4 * g + r) * Cc + 16 * df + lo] = f2bf(o[mf][df][r]);
}

// -------------------------------- launcher --------------------------------------
extern "C" void kernel_launch(void* const* d_in, const int* in_sizes, int n_in,
                              void* d_out, int out_size, void* d_ws, size_t ws_size,
                              hipStream_t stream) {
    const float* x      = (const float*)d_in[0];
    const float* skip   = (const float*)d_in[2];
    const float* x_up   = (const float*)d_in[3];
    const float* n1g    = (const float*)d_in[4];
    const float* n1b    = (const float*)d_in[5];
    const float* kv_w   = (const float*)d_in[6];
    const float* kv_b   = (const float*)d_in[7];
    const float* rpb    = (const float*)d_in[8];
    const float* proj_w = (const float*)d_in[9];
    const float* proj_b = (const float*)d_in[10];
    const float* n2g    = (const float*)d_in[11];
    const float* n2b    = (const float*)d_in[12];
    const float* fc1_w  = (const float*)d_in[13];
    const float* fc1_b  = (const float*)d_in[14];
    const float* fc2_w  = (const float*)d_in[15];
    const float* fc2_b  = (const float*)d_in[16];
    float* out = (float*)d_out;

    char* ws = (char*)d_ws;
    ushort* skip_w = (ushort*)ws;                       // 12,582,912 B
    ushort* xup_w  = (ushort*)(ws + 12582912);
    ushort* k_buf  = (ushort*)(ws + 25165824);          // bf16 [win][head][n][d]
    ushort* v_bufT = (ushort*)(ws + 37748736);          // bf16 [win][head][d][n]
    ushort* attn_o = (ushort*)(ws + 50331648);
    float*  x_buf  = (float*)(ws + 62914560);           // 25,165,824 B
    ushort* h_norm = (ushort*)(ws + 88080384);
    ushort* h1     = (ushort*)ws;                       // 50,331,648 B overlay (dead bufs)
    char* wp = ws + 100663296;
    ushort* kv_wp   = (ushort*)wp;
    ushort* proj_wp = (ushort*)(wp + 147456);
    ushort* fc1_wp  = (ushort*)(wp + 221184);
    ushort* fc2_wp  = (ushort*)(wp + 516096);
    float*  biasF   = (float*)(wp + 811008);            // 98,304 B

    pack_w<<<(192 * 384 + 255) / 256, 256, 0, stream>>>(kv_w, kv_wp, 192 * 384, 384);
    pack_w<<<(192 * 192 + 255) / 256, 256, 0, stream>>>(proj_w, proj_wp, 192 * 192, 192);
    pack_w<<<(192 * 768 + 255) / 256, 256, 0, stream>>>(fc1_w, fc1_wp, 192 * 768, 768);
    pack_w<<<(768 * 192 + 255) / 256, 256, 0, stream>>>(fc2_w, fc2_wp, 768 * 192, 192);
    pack_bias<<<24, 256, 0, stream>>>(rpb, biasF);

    ln_kernel<<<ROWS / 4, 256, 0, stream>>>(skip, n1g, n1b, skip_w, 1);
    ln_kernel<<<ROWS / 4, 256, 0, stream>>>(x_up, n1g, n1b, xup_w, 1);
    mgemm<EPI_KV><<<dim3(ROWS / 128, 384 / 64), 256, 0, stream>>>(
        skip_w, kv_wp, kv_b, nullptr, ROWS, 384, Cc, nullptr, k_buf, v_bufT);
    attn_kernel<<<NWIN * NHEAD / 4, 256, 0, stream>>>(xup_w, k_buf, v_bufT, biasF, attn_o);
    mgemm<EPI_PROJ><<<dim3(ROWS / 128, Cc / 64), 256, 0, stream>>>(
        attn_o, proj_wp, proj_b, x_buf, ROWS, Cc, Cc, x, nullptr, nullptr);
    ln_kernel<<<ROWS / 4, 256, 0, stream>>>(x_buf, n2g, n2b, h_norm, 0);
    mgemm<EPI_FC1><<<dim3(ROWS / 128, HIDDEN / 64), 256, 0, stream>>>(
        h_norm, fc1_wp, fc1_b, nullptr, ROWS, HIDDEN, Cc, nullptr, h1, nullptr);
    mgemm<EPI_FC2><<<dim3(ROWS / 128, Cc / 64), 256, 0, stream>>>(
        h1, fc2_wp, fc2_b, out, ROWS, Cc, HIDDEN, x_buf, nullptr, nullptr);
}